// Round 4
// baseline (268.654 us; speedup 1.0000x reference)
//
#include <hip/hip_runtime.h>
#include <hip/hip_bf16.h>
#include <stdint.h>

// ---------- helpers ----------
typedef __attribute__((ext_vector_type(8))) short s16x8;
typedef __attribute__((ext_vector_type(4))) float f32x4;

__device__ __forceinline__ unsigned short f2bf(float f) {
  union { float f; unsigned int u; } v; v.f = f;
  unsigned int r = (v.u + 0x7fffu + ((v.u >> 16) & 1u)) >> 16;
  return (unsigned short)r;
}
__device__ __forceinline__ float bf2f(unsigned short h) {
  union { float f; unsigned int u; } v; v.u = ((unsigned int)h) << 16; return v.f;
}

// async global->LDS, 16B per lane; lds base must be wave-uniform, HW adds lane*16
__device__ __forceinline__ void async_copy16(const unsigned short* g, unsigned short* lds_base) {
  __builtin_amdgcn_global_load_lds(
      (const __attribute__((address_space(1))) unsigned int*)g,
      (__attribute__((address_space(3))) unsigned int*)lds_base,
      16, 0, 0);
}

template <int N> __device__ __forceinline__ void wait_vmcnt() {
  if constexpr (N == 0)      asm volatile("s_waitcnt vmcnt(0)" ::: "memory");
  else if constexpr (N == 2) asm volatile("s_waitcnt vmcnt(2)" ::: "memory");
  else if constexpr (N == 3) asm volatile("s_waitcnt vmcnt(3)" ::: "memory");
  else if constexpr (N == 9) asm volatile("s_waitcnt vmcnt(9)" ::: "memory");
  else static_assert(N == 0 || N == 2 || N == 3 || N == 9, "add vmcnt case");
}

// ---------- fp32 -> bf16 convert (two arrays in one launch) ----------
__global__ __launch_bounds__(256) void cvt2_kernel(const float* __restrict__ s1,
                                                   unsigned short* __restrict__ d1, int n1_4,
                                                   const float* __restrict__ s2,
                                                   unsigned short* __restrict__ d2, int n2_4) {
  int i = blockIdx.x * 256 + threadIdx.x;
  const float* s; unsigned short* d; int idx;
  if (i < n1_4) { s = s1; d = d1; idx = i; }
  else if (i < n1_4 + n2_4) { s = s2; d = d2; idx = i - n1_4; }
  else return;
  float4 v = ((const float4*)s)[idx];
  ushort4 o;
  o.x = f2bf(v.x); o.y = f2bf(v.y); o.z = f2bf(v.z); o.w = f2bf(v.w);
  ((ushort4*)d)[idx] = o;
}

// ---------- LayerNorm: one block per row of 1024 ----------
__global__ __launch_bounds__(256) void ln_kernel(const float* __restrict__ x,
                                                 const float* __restrict__ gamma,
                                                 const float* __restrict__ beta,
                                                 unsigned short* __restrict__ h) {
  const int row = blockIdx.x;
  const int t = threadIdx.x;
  const float4 v = ((const float4*)(x + (size_t)row * 1024))[t];
  float s  = v.x + v.y + v.z + v.w;
  float s2 = v.x*v.x + v.y*v.y + v.z*v.z + v.w*v.w;
#pragma unroll
  for (int o = 32; o > 0; o >>= 1) {
    s  += __shfl_down(s,  o, 64);
    s2 += __shfl_down(s2, o, 64);
  }
  __shared__ float rs[4], rs2[4];
  const int wid = t >> 6;
  if ((t & 63) == 0) { rs[wid] = s; rs2[wid] = s2; }
  __syncthreads();
  const float S  = rs[0] + rs[1] + rs[2] + rs[3];
  const float S2 = rs2[0] + rs2[1] + rs2[2] + rs2[3];
  const float mu  = S * (1.f / 1024.f);
  const float inv = rsqrtf(S2 * (1.f / 1024.f) - mu * mu + 1e-5f);
  const float4 g = ((const float4*)gamma)[t];
  const float4 b = ((const float4*)beta)[t];
  ushort4 o;
  o.x = f2bf((v.x - mu) * inv * g.x + b.x);
  o.y = f2bf((v.y - mu) * inv * g.y + b.y);
  o.z = f2bf((v.z - mu) * inv * g.z + b.z);
  o.w = f2bf((v.w - mu) * inv * g.w + b.w);
  ((ushort4*)(h + (size_t)row * 1024))[t] = o;
}

// ---------- q/k projection from base = uv[:, 2E : 2E+S] ----------
__global__ __launch_bounds__(256) void qk_kernel(const unsigned short* __restrict__ uv,
                                                 const float* __restrict__ qkw,
                                                 const float* __restrict__ qkb,
                                                 unsigned short* __restrict__ q,
                                                 unsigned short* __restrict__ k,
                                                 int NU, int baseoff, int S, int total) {
  int i = blockIdx.x * 256 + threadIdx.x;
  if (i < total) {
    int n = i / S, s = i - n * S;
    float base = bf2f(uv[(size_t)n * NU + baseoff + s]);
    q[i] = f2bf(base * qkw[s]     + qkb[s]);
    k[i] = f2bf(base * qkw[S + s] + qkb[S + s]);
  }
}

// ---------- transpose v: vT[e][m] = uv[m][E + e] ----------
__global__ __launch_bounds__(256) void transpose_v(const unsigned short* __restrict__ uv,
                                                   unsigned short* __restrict__ vT,
                                                   int n, int NU, int E) {
  __shared__ unsigned short tile[64][68];
  const int tm = blockIdx.x * 64;
  const int te = blockIdx.y * 64;
  const int t = threadIdx.x;
  const int r  = t >> 4;
  const int c4 = (t & 15) * 4;
#pragma unroll
  for (int i = 0; i < 4; ++i) {
    int row = i * 16 + r;
    ushort4 v = *(const ushort4*)(uv + (size_t)(tm + row) * NU + E + te + c4);
    tile[row][c4 + 0] = v.x; tile[row][c4 + 1] = v.y;
    tile[row][c4 + 2] = v.z; tile[row][c4 + 3] = v.w;
  }
  __syncthreads();
#pragma unroll
  for (int i = 0; i < 4; ++i) {
    int erow = i * 16 + r;
    ushort4 o;
    o.x = tile[c4 + 0][erow]; o.y = tile[c4 + 1][erow];
    o.z = tile[c4 + 2][erow]; o.w = tile[c4 + 3][erow];
    *(ushort4*)(vT + (size_t)(te + erow) * n + tm + c4) = o;
  }
}

// ---------- pipelined GEMM: BM x 128 tile, BK=32, (LA+1)-buffer lookahead-LA ----------
// R2-proven phase shape, one phase per K-tile of 32:
//   { stage 3 (or 2) gloads for t+LA -> wb ; 8 (or 6) ds_read_b128 from rb ;
//     s_barrier ; lgkmcnt(0) ; setprio(1) 16 (or 8) MFMA setprio(0) ;
//     counted vmcnt (never 0 in steady state) ; s_barrier }
// LDS rows are 64B (32 bf16): row-pair packed into 128B lines, 16B slots XOR-
// swizzled by (line&3) so fragment ds_read_b128 is conflict-free (2-way only).
// Both-sides swizzle (rule #21): gload SOURCE address pre-swizzled, LDS linear.
// Race-freedom: buffer b read at tile t is next written by the stage issued
// during tile t+1 (for tile t+NBUF); tile t's end-barrier separates them.
// Boundary vmcnt retires tile t+1's loads, keeps LA-1 tiles' loads in flight.
// BM=256: 8 waves 4Mx2N, per-wave 64x64, acc[4][4]; LDS/buf 24KB.
// BM=128: 8 waves 2Mx4N, per-wave 64x32, acc[4][2]; LDS/buf 16KB.
// EPI 0: silu(acc + bias[col])          -> bf16 D
// EPI 1: (max(acc,0))^2 / 128           -> bf16 D
// EPI 2: acc * U[row][col]              -> bf16 D
// EPI 3: acc + bias[col] + X[row][col]  -> f32  D
template <int EPI, int BM, int LA>
__global__ __launch_bounds__(512, 4) void gemm_pipe(const unsigned short* __restrict__ A, int lda,
                                                    const unsigned short* __restrict__ B, int ldb,
                                                    void* __restrict__ D, int ldd, int K,
                                                    const float* __restrict__ bias,
                                                    const unsigned short* __restrict__ U, int ldu,
                                                    const float* __restrict__ X, int ldx) {
  constexpr int NBUF  = LA + 1;
  constexpr int AIT   = BM / 128;        // A gload instrs per K-tile
  constexpr int LPT   = AIT + 1;         // loads per tile
  constexpr int NN    = (BM == 256) ? 4 : 2;
  constexpr int WN    = NN * 16;         // wave col-band width
  constexpr int VMS   = LPT * (LA - 1);  // steady-state vmcnt immediate

  __shared__ unsigned short As[NBUF][BM * 32];
  __shared__ unsigned short Bs[NBUF][128 * 32];

  const int tid  = threadIdx.x;
  const int wid  = tid >> 6;
  const int lane = tid & 63;
  const int bm = blockIdx.x * BM;
  const int bn = blockIdx.y * 128;
  const int wr = (BM == 256) ? (wid >> 1) : (wid >> 2);
  const int wc = (BM == 256) ? (wid & 1)  : (wid & 3);

  // fragment read addressing (elems): addr = row*32 + fk, fk swizzled per lane
  const int frow = lane & 15;
  const int fk   = (((lane >> 4) ^ ((lane >> 1) & 3)) * 8);

  // staging: per gload instr, 512 threads cover 128 rows x 32 cols (8KB).
  // lane l of wave w writes LDS bytes [wavebase + l*16); that slot holds
  // row = w*16 + (l>>3)*2 + ((l>>2)&1), kslot = (l&3) ^ ((l>>3)&3).
  const int rowoff = (tid >> 6) * 16 + ((tid >> 3) & 7) * 2 + ((tid >> 2) & 1);
  const int koff   = (((tid & 3) ^ ((tid >> 3) & 3)) * 8);
  const unsigned short* pA = A + (size_t)(bm + rowoff) * lda + koff;
  const unsigned short* pB = B + (size_t)(bn + rowoff) * ldb + koff;

  const int NT = K >> 5;   // K-tiles of 32 (requires NT >= LA)

  // prologue: stage tiles 0..LA-1 into bufs 0..LA-1, wait tile0 (keep LA-1 in flight)
#pragma unroll
  for (int p = 0; p < LA; ++p) {
#pragma unroll
    for (int i = 0; i < AIT; ++i)
      async_copy16(pA + (size_t)(i * 128) * lda + p * 32, &As[p][i * 4096 + wid * 512]);
    async_copy16(pB + p * 32, &Bs[p][wid * 512]);
  }
  wait_vmcnt<VMS>();
  __builtin_amdgcn_s_barrier();
  __builtin_amdgcn_sched_barrier(0);

  f32x4 acc[4][NN] = {};
  int rb = 0, wb = LA;

  for (int t = 0; t < NT; ++t) {
    const bool pref = (t + LA) < NT;
    if (pref) {
      const int kp = (t + LA) << 5;
#pragma unroll
      for (int i = 0; i < AIT; ++i)
        async_copy16(pA + (size_t)(i * 128) * lda + kp, &As[wb][i * 4096 + wid * 512]);
      async_copy16(pB + kp, &Bs[wb][wid * 512]);
    }
    s16x8 a[4], b[NN];
#pragma unroll
    for (int m = 0; m < 4; ++m)
      a[m] = *(const s16x8*)&As[rb][(wr * 64 + m * 16 + frow) * 32 + fk];
#pragma unroll
    for (int n = 0; n < NN; ++n)
      b[n] = *(const s16x8*)&Bs[rb][(wc * WN + n * 16 + frow) * 32 + fk];
    __builtin_amdgcn_s_barrier();
    asm volatile("s_waitcnt lgkmcnt(0)" ::: "memory");
    __builtin_amdgcn_sched_barrier(0);
    __builtin_amdgcn_s_setprio(1);
#pragma unroll
    for (int m = 0; m < 4; ++m)
#pragma unroll
      for (int n = 0; n < NN; ++n)
        acc[m][n] = __builtin_amdgcn_mfma_f32_16x16x32_bf16(a[m], b[n], acc[m][n], 0, 0, 0);
    __builtin_amdgcn_s_setprio(0);
    if (pref) { wait_vmcnt<VMS>(); }
    else      { wait_vmcnt<0>(); }
    __builtin_amdgcn_s_barrier();
    __builtin_amdgcn_sched_barrier(0);
    rb = (rb == NBUF - 1) ? 0 : rb + 1;
    wb = (wb == NBUF - 1) ? 0 : wb + 1;
  }

  // epilogue
  const int rbase = (lane >> 4) * 4;
  const int cloc  = lane & 15;
#pragma unroll
  for (int m = 0; m < 4; ++m) {
#pragma unroll
    for (int n = 0; n < NN; ++n) {
      const int col = bn + wc * WN + n * 16 + cloc;
#pragma unroll
      for (int r = 0; r < 4; ++r) {
        const int row = bm + wr * 64 + m * 16 + rbase + r;
        float v = acc[m][n][r];
        if constexpr (EPI == 0) {
          v += bias[col];
          float sv = v / (1.f + __expf(-v));
          ((unsigned short*)D)[(size_t)row * ldd + col] = f2bf(sv);
        } else if constexpr (EPI == 1) {
          float z = fmaxf(v, 0.f);
          ((unsigned short*)D)[(size_t)row * ldd + col] = f2bf(z * z * (1.f / 128.f));
        } else if constexpr (EPI == 2) {
          float u = bf2f(U[(size_t)row * ldu + col]);
          ((unsigned short*)D)[(size_t)row * ldd + col] = f2bf(v * u);
        } else {
          ((float*)D)[(size_t)row * ldd + col] = v + bias[col] + X[(size_t)row * ldx + col];
        }
      }
    }
  }
}

// ---------- launch ----------
extern "C" void kernel_launch(void* const* d_in, const int* in_sizes, int n_in,
                              void* d_out, int out_size, void* d_ws, size_t ws_size,
                              hipStream_t stream) {
  const float* x    = (const float*)d_in[0];
  const float* ln_g = (const float*)d_in[1];
  const float* ln_b = (const float*)d_in[2];
  const float* uv_w = (const float*)d_in[3];
  const float* uv_b = (const float*)d_in[4];
  const float* qk_w = (const float*)d_in[5];
  const float* qk_b = (const float*)d_in[6];
  const float* o_w  = (const float*)d_in[7];
  const float* o_b  = (const float*)d_in[8];
  float* out = (float*)d_out;

  const int H = 1024, E = 2048, S = 128;
  const int NU = 2 * E + S;          // 4224
  const int n = in_sizes[0] / H;     // 4096

  char* p = (char*)d_ws;
  unsigned short* h_bf   = (unsigned short*)p; p += (size_t)n * H * 2;
  unsigned short* uvw_bf = (unsigned short*)p; p += (size_t)NU * H * 2;
  unsigned short* ow_bf  = (unsigned short*)p; p += (size_t)H * E * 2;
  unsigned short* uv_bf  = (unsigned short*)p; p += (size_t)n * NU * 2;
  unsigned short* q_bf   = (unsigned short*)p; p += (size_t)n * S * 2;
  unsigned short* k_bf   = (unsigned short*)p; p += (size_t)n * S * 2;
  unsigned short* vT_bf  = (unsigned short*)p; p += (size_t)E * n * 2;
  unsigned short* ker_bf = (unsigned short*)p; p += (size_t)n * n * 2;
  unsigned short* ug_bf  = (unsigned short*)p; p += (size_t)n * E * 2;

  const int n1_4 = NU * H / 4, n2_4 = H * E / 4;
  cvt2_kernel<<<(n1_4 + n2_4 + 255) / 256, 256, 0, stream>>>(uv_w, uvw_bf, n1_4, o_w, ow_bf, n2_4);

  ln_kernel<<<n, 256, 0, stream>>>(x, ln_g, ln_b, h_bf);

  // uv = silu(h @ uv_w^T + uv_b)   M=4096 N=4224 K=1024 ; 528 blocks, 2/CU
  gemm_pipe<0, 256, 2><<<dim3(n / 256, NU / 128), 512, 0, stream>>>(
      h_bf, H, uvw_bf, H, uv_bf, NU, H, uv_b, nullptr, 0, nullptr, 0);

  int tq = n * S;
  qk_kernel<<<(tq + 255) / 256, 256, 0, stream>>>(uv_bf, qk_w, qk_b, q_bf, k_bf, NU, 2 * E, S, tq);

  transpose_v<<<dim3(n / 64, E / 64), 256, 0, stream>>>(uv_bf, vT_bf, n, NU, E);

  // kernel = relu(q @ k^T / sqrt(128))^2   M=N=4096 K=128 ; 512 blocks, 2/CU
  gemm_pipe<1, 256, 2><<<dim3(n / 256, n / 128), 512, 0, stream>>>(
      q_bf, S, k_bf, S, ker_bf, n, S, nullptr, nullptr, 0, nullptr, 0);

  // ug = u * (kernel @ v)   M=4096 N=2048 K=4096 ; 256 blocks, deep pipe (LA=4)
  gemm_pipe<2, 256, 4><<<dim3(n / 256, E / 128), 512, 0, stream>>>(
      ker_bf, n, vT_bf, n, ug_bf, E, n, nullptr, uv_bf, NU, nullptr, 0);

  // out = ug @ o_w^T + o_b + x   M=4096 N=1024 K=2048 ; BM=128 -> 256 blocks full machine
  gemm_pipe<3, 128, 2><<<dim3(n / 128, H / 128), 512, 0, stream>>>(
      ug_bf, E, ow_bf, E, out, H, E, o_b, nullptr, 0, x, H);
}

// Round 5
// 200.080 us; speedup vs baseline: 1.3427x; 1.3427x over previous
//
#include <hip/hip_runtime.h>
#include <hip/hip_bf16.h>
#include <stdint.h>

// ---------- helpers ----------
typedef __attribute__((ext_vector_type(8))) short s16x8;
typedef __attribute__((ext_vector_type(4))) float f32x4;

__device__ __forceinline__ unsigned short f2bf(float f) {
  union { float f; unsigned int u; } v; v.f = f;
  unsigned int r = (v.u + 0x7fffu + ((v.u >> 16) & 1u)) >> 16;
  return (unsigned short)r;
}
__device__ __forceinline__ float bf2f(unsigned short h) {
  union { float f; unsigned int u; } v; v.u = ((unsigned int)h) << 16; return v.f;
}

// async global->LDS, 16B per lane; lds base must be wave-uniform, HW adds lane*16
__device__ __forceinline__ void async_copy16(const unsigned short* g, unsigned short* lds_base) {
  __builtin_amdgcn_global_load_lds(
      (const __attribute__((address_space(1))) unsigned int*)g,
      (__attribute__((address_space(3))) unsigned int*)lds_base,
      16, 0, 0);
}

template <int N> __device__ __forceinline__ void wait_vmcnt() {
  if constexpr (N == 0)      asm volatile("s_waitcnt vmcnt(0)" ::: "memory");
  else if constexpr (N == 4) asm volatile("s_waitcnt vmcnt(4)" ::: "memory");
  else if constexpr (N == 6) asm volatile("s_waitcnt vmcnt(6)" ::: "memory");
  else static_assert(N == 0 || N == 4 || N == 6, "add vmcnt case");
}

// ---------- fp32 -> bf16 convert (two arrays in one launch) ----------
__global__ __launch_bounds__(256) void cvt2_kernel(const float* __restrict__ s1,
                                                   unsigned short* __restrict__ d1, int n1_4,
                                                   const float* __restrict__ s2,
                                                   unsigned short* __restrict__ d2, int n2_4) {
  int i = blockIdx.x * 256 + threadIdx.x;
  const float* s; unsigned short* d; int idx;
  if (i < n1_4) { s = s1; d = d1; idx = i; }
  else if (i < n1_4 + n2_4) { s = s2; d = d2; idx = i - n1_4; }
  else return;
  float4 v = ((const float4*)s)[idx];
  ushort4 o;
  o.x = f2bf(v.x); o.y = f2bf(v.y); o.z = f2bf(v.z); o.w = f2bf(v.w);
  ((ushort4*)d)[idx] = o;
}

// ---------- LayerNorm: one block per row of 1024 ----------
__global__ __launch_bounds__(256) void ln_kernel(const float* __restrict__ x,
                                                 const float* __restrict__ gamma,
                                                 const float* __restrict__ beta,
                                                 unsigned short* __restrict__ h) {
  const int row = blockIdx.x;
  const int t = threadIdx.x;
  const float4 v = ((const float4*)(x + (size_t)row * 1024))[t];
  float s  = v.x + v.y + v.z + v.w;
  float s2 = v.x*v.x + v.y*v.y + v.z*v.z + v.w*v.w;
#pragma unroll
  for (int o = 32; o > 0; o >>= 1) {
    s  += __shfl_down(s,  o, 64);
    s2 += __shfl_down(s2, o, 64);
  }
  __shared__ float rs[4], rs2[4];
  const int wid = t >> 6;
  if ((t & 63) == 0) { rs[wid] = s; rs2[wid] = s2; }
  __syncthreads();
  const float S  = rs[0] + rs[1] + rs[2] + rs[3];
  const float S2 = rs2[0] + rs2[1] + rs2[2] + rs2[3];
  const float mu  = S * (1.f / 1024.f);
  const float inv = rsqrtf(S2 * (1.f / 1024.f) - mu * mu + 1e-5f);
  const float4 g = ((const float4*)gamma)[t];
  const float4 b = ((const float4*)beta)[t];
  ushort4 o;
  o.x = f2bf((v.x - mu) * inv * g.x + b.x);
  o.y = f2bf((v.y - mu) * inv * g.y + b.y);
  o.z = f2bf((v.z - mu) * inv * g.z + b.z);
  o.w = f2bf((v.w - mu) * inv * g.w + b.w);
  ((ushort4*)(h + (size_t)row * 1024))[t] = o;
}

// ---------- q/k projection from base = uv[:, 2E : 2E+S] ----------
__global__ __launch_bounds__(256) void qk_kernel(const unsigned short* __restrict__ uv,
                                                 const float* __restrict__ qkw,
                                                 const float* __restrict__ qkb,
                                                 unsigned short* __restrict__ q,
                                                 unsigned short* __restrict__ k,
                                                 int NU, int baseoff, int S, int total) {
  int i = blockIdx.x * 256 + threadIdx.x;
  if (i < total) {
    int n = i / S, s = i - n * S;
    float base = bf2f(uv[(size_t)n * NU + baseoff + s]);
    q[i] = f2bf(base * qkw[s]     + qkb[s]);
    k[i] = f2bf(base * qkw[S + s] + qkb[S + s]);
  }
}

// ---------- transpose v: vT[e][m] = uv[m][E + e] ----------
__global__ __launch_bounds__(256) void transpose_v(const unsigned short* __restrict__ uv,
                                                   unsigned short* __restrict__ vT,
                                                   int n, int NU, int E) {
  __shared__ unsigned short tile[64][68];
  const int tm = blockIdx.x * 64;
  const int te = blockIdx.y * 64;
  const int t = threadIdx.x;
  const int r  = t >> 4;
  const int c4 = (t & 15) * 4;
#pragma unroll
  for (int i = 0; i < 4; ++i) {
    int row = i * 16 + r;
    ushort4 v = *(const ushort4*)(uv + (size_t)(tm + row) * NU + E + te + c4);
    tile[row][c4 + 0] = v.x; tile[row][c4 + 1] = v.y;
    tile[row][c4 + 2] = v.z; tile[row][c4 + 3] = v.w;
  }
  __syncthreads();
#pragma unroll
  for (int i = 0; i < 4; ++i) {
    int erow = i * 16 + r;
    ushort4 o;
    o.x = tile[c4 + 0][erow]; o.y = tile[c4 + 1][erow];
    o.z = tile[c4 + 2][erow]; o.w = tile[c4 + 3][erow];
    *(ushort4*)(vT + (size_t)(te + erow) * n + tm + c4) = o;
  }
}

// ---------- pipelined GEMM: BMx128 tile, BK=64, NBUF=3, reg-double-buffered ----------
// Per K-tile t (ONE barrier per tile):
//   stage(t+2 -> buf[(t+2)%3]) ; vmcnt(6) [counted, retires loads(t+1), keeps
//   t+2's 6 in flight] ; s_barrier ; sched_barrier ;
//   ds_read 16 frags of tile t+1 -> NEXT reg set ;
//   setprio(1) 32 MFMA on CUR reg set setprio(0) ;   // overlaps the ds_reads
//   lgkmcnt(0) ; sched_barrier                        // lands after MFMA: ~free
// Race-freedom: buf((t+2)%3)'s prior tenant (t-1) was ds_read before iter t-1's
// barrier (lgkm(0) closed in iter t-2 body); stage issues after that barrier.
// reads(t+1) come after iter t's barrier, which follows every wave's vmcnt(6)
// retiring its share of loads(t+1). vmcnt never 0 in steady state.
// Staging geometry identical to the R2-proven pattern (wave = 8 rows x 128B,
// source-slot XOR pre-swizzle; read-side XOR swizzle; rule #21 both-sides).
// BM=256: 8 waves 4Mx2N, per-wave 64x64, acc[4][4]; LDS 144KB.
// BM=128: 8 waves 2Mx4N, per-wave 64x32, acc[4][2]; LDS  96KB.
// NT = K/64 must be even and >= 2 (16/2/64/32 here).
// EPI 0: silu(acc + bias[col])          -> bf16 D
// EPI 1: (max(acc,0))^2 / 128           -> bf16 D
// EPI 2: acc * U[row][col]              -> bf16 D
// EPI 3: acc + bias[col] + X[row][col]  -> f32  D
template <int EPI, int BM>
__global__ __launch_bounds__(512, 2) void gemm_pipe(const unsigned short* __restrict__ A, int lda,
                                                    const unsigned short* __restrict__ B, int ldb,
                                                    void* __restrict__ D, int ldd, int K,
                                                    const float* __restrict__ bias,
                                                    const unsigned short* __restrict__ U, int ldu,
                                                    const float* __restrict__ X, int ldx) {
  constexpr int AIT = BM / 64;           // A gloads per tile (256->4, 128->2)
  constexpr int BIT = 2;                 // B gloads per tile
  constexpr int VMS = AIT + BIT;         // steady-state vmcnt (one tile in flight)
  constexpr int NN  = (BM == 256) ? 4 : 2;
  constexpr int WN  = NN * 16;

  __shared__ unsigned short As[3][BM * 64];
  __shared__ unsigned short Bs[3][128 * 64];

  const int tid  = threadIdx.x;
  const int wid  = tid >> 6;
  const int lane = tid & 63;
  const int bm = blockIdx.x * BM;
  const int bn = blockIdx.y * 128;
  const int wr = (BM == 256) ? (wid >> 1) : (wid >> 2);
  const int wc = (BM == 256) ? (wid & 1)  : (wid & 3);
  const int frow = lane & 15;
  const int kgrp = (lane >> 4) * 8;
  const int swz  = (frow & 7) * 8;       // read-side XOR swizzle (elements)

  // staging: per gload instr, 512 threads cover 64 rows x 128B (wave = 8 rows)
  const int srow  = tid >> 3;                     // 0..63
  const int sslot = (tid & 7) ^ (srow & 7);       // source-slot pre-swizzle
  const unsigned short* pA = A + (size_t)(bm + srow) * lda + sslot * 8;
  const unsigned short* pB = B + (size_t)(bn + srow) * ldb + sslot * 8;

#define STAGE(bufidx, k0)                                                                   \
  {                                                                                         \
    _Pragma("unroll")                                                                       \
    for (int i = 0; i < AIT; ++i)                                                           \
      async_copy16(pA + (size_t)(i * 64) * lda + (k0), &As[bufidx][(i * 64 + wid * 8) * 64]); \
    _Pragma("unroll")                                                                       \
    for (int j = 0; j < BIT; ++j)                                                           \
      async_copy16(pB + (size_t)(j * 64) * ldb + (k0), &Bs[bufidx][(j * 64 + wid * 8) * 64]); \
  }

#define READ_FRAGS(rbuf, NA, NB)                                                            \
  {                                                                                         \
    _Pragma("unroll")                                                                       \
    for (int ks = 0; ks < 2; ++ks) {                                                        \
      _Pragma("unroll")                                                                     \
      for (int m = 0; m < 4; ++m)                                                           \
        NA[ks][m] = *(const s16x8*)&As[rbuf][(wr * 64 + m * 16 + frow) * 64 +               \
                                            ((ks * 32 + kgrp) ^ swz)];                      \
      _Pragma("unroll")                                                                     \
      for (int n = 0; n < NN; ++n)                                                          \
        NB[ks][n] = *(const s16x8*)&Bs[rbuf][(wc * WN + n * 16 + frow) * 64 +               \
                                            ((ks * 32 + kgrp) ^ swz)];                      \
    }                                                                                       \
  }

#define MFMA_ALL(CA, CB)                                                                    \
  {                                                                                         \
    _Pragma("unroll")                                                                       \
    for (int ks = 0; ks < 2; ++ks)                                                          \
      _Pragma("unroll")                                                                     \
      for (int m = 0; m < 4; ++m)                                                           \
        _Pragma("unroll")                                                                   \
        for (int n = 0; n < NN; ++n)                                                        \
          acc[m][n] = __builtin_amdgcn_mfma_f32_16x16x32_bf16(CA[ks][m], CB[ks][n],         \
                                                              acc[m][n], 0, 0, 0);          \
  }

#define PIPE_STEP(t, CA, CB, NA, NB)                                                        \
  {                                                                                         \
    if ((t) + 2 < NT) {                                                                     \
      STAGE(((t) + 2) % 3, ((t) + 2) << 6);                                                 \
      wait_vmcnt<VMS>();                                                                    \
    } else {                                                                                \
      wait_vmcnt<0>();                                                                      \
    }                                                                                       \
    __builtin_amdgcn_s_barrier();                                                           \
    __builtin_amdgcn_sched_barrier(0);                                                      \
    if ((t) + 1 < NT) { READ_FRAGS(((t) + 1) % 3, NA, NB); }                                \
    __builtin_amdgcn_s_setprio(1);                                                          \
    MFMA_ALL(CA, CB);                                                                       \
    __builtin_amdgcn_s_setprio(0);                                                          \
    asm volatile("s_waitcnt lgkmcnt(0)" ::: "memory");                                      \
    __builtin_amdgcn_sched_barrier(0);                                                      \
  }

  const int NT = K >> 6;   // K-tiles of 64; must be even, >= 2

  // prologue: stage tiles 0,1; tile0 resident (keep tile1's 6 in flight); frags0 -> set0
  STAGE(0, 0);
  STAGE(1, 64);
  wait_vmcnt<VMS>();
  __builtin_amdgcn_s_barrier();
  __builtin_amdgcn_sched_barrier(0);

  f32x4 acc[4][NN] = {};
  s16x8 a0[2][4], b0[2][NN], a1[2][4], b1[2][NN];
  READ_FRAGS(0, a0, b0);
  asm volatile("s_waitcnt lgkmcnt(0)" ::: "memory");
  __builtin_amdgcn_sched_barrier(0);

  for (int t = 0; t < NT; t += 2) {
    PIPE_STEP(t,     a0, b0, a1, b1);
    PIPE_STEP(t + 1, a1, b1, a0, b0);
  }

#undef STAGE
#undef READ_FRAGS
#undef MFMA_ALL
#undef PIPE_STEP

  // epilogue
  const int rbase = (lane >> 4) * 4;
  const int cloc  = lane & 15;
#pragma unroll
  for (int m = 0; m < 4; ++m) {
#pragma unroll
    for (int n = 0; n < NN; ++n) {
      const int col = bn + wc * WN + n * 16 + cloc;
#pragma unroll
      for (int r = 0; r < 4; ++r) {
        const int row = bm + wr * 64 + m * 16 + rbase + r;
        float v = acc[m][n][r];
        if constexpr (EPI == 0) {
          v += bias[col];
          float sv = v / (1.f + __expf(-v));
          ((unsigned short*)D)[(size_t)row * ldd + col] = f2bf(sv);
        } else if constexpr (EPI == 1) {
          float z = fmaxf(v, 0.f);
          ((unsigned short*)D)[(size_t)row * ldd + col] = f2bf(z * z * (1.f / 128.f));
        } else if constexpr (EPI == 2) {
          float u = bf2f(U[(size_t)row * ldu + col]);
          ((unsigned short*)D)[(size_t)row * ldd + col] = f2bf(v * u);
        } else {
          ((float*)D)[(size_t)row * ldd + col] = v + bias[col] + X[(size_t)row * ldx + col];
        }
      }
    }
  }
}

// ---------- launch ----------
extern "C" void kernel_launch(void* const* d_in, const int* in_sizes, int n_in,
                              void* d_out, int out_size, void* d_ws, size_t ws_size,
                              hipStream_t stream) {
  const float* x    = (const float*)d_in[0];
  const float* ln_g = (const float*)d_in[1];
  const float* ln_b = (const float*)d_in[2];
  const float* uv_w = (const float*)d_in[3];
  const float* uv_b = (const float*)d_in[4];
  const float* qk_w = (const float*)d_in[5];
  const float* qk_b = (const float*)d_in[6];
  const float* o_w  = (const float*)d_in[7];
  const float* o_b  = (const float*)d_in[8];
  float* out = (float*)d_out;

  const int H = 1024, E = 2048, S = 128;
  const int NU = 2 * E + S;          // 4224
  const int n = in_sizes[0] / H;     // 4096

  char* p = (char*)d_ws;
  unsigned short* h_bf   = (unsigned short*)p; p += (size_t)n * H * 2;
  unsigned short* uvw_bf = (unsigned short*)p; p += (size_t)NU * H * 2;
  unsigned short* ow_bf  = (unsigned short*)p; p += (size_t)H * E * 2;
  unsigned short* uv_bf  = (unsigned short*)p; p += (size_t)n * NU * 2;
  unsigned short* q_bf   = (unsigned short*)p; p += (size_t)n * S * 2;
  unsigned short* k_bf   = (unsigned short*)p; p += (size_t)n * S * 2;
  unsigned short* vT_bf  = (unsigned short*)p; p += (size_t)E * n * 2;
  unsigned short* ker_bf = (unsigned short*)p; p += (size_t)n * n * 2;
  unsigned short* ug_bf  = (unsigned short*)p; p += (size_t)n * E * 2;

  const int n1_4 = NU * H / 4, n2_4 = H * E / 4;
  cvt2_kernel<<<(n1_4 + n2_4 + 255) / 256, 256, 0, stream>>>(uv_w, uvw_bf, n1_4, o_w, ow_bf, n2_4);

  ln_kernel<<<n, 256, 0, stream>>>(x, ln_g, ln_b, h_bf);

  // uv = silu(h @ uv_w^T + uv_b)   M=4096 N=4224 K=1024 (NT=16)
  gemm_pipe<0, 256><<<dim3(n / 256, NU / 128), 512, 0, stream>>>(
      h_bf, H, uvw_bf, H, uv_bf, NU, H, uv_b, nullptr, 0, nullptr, 0);

  int tq = n * S;
  qk_kernel<<<(tq + 255) / 256, 256, 0, stream>>>(uv_bf, qk_w, qk_b, q_bf, k_bf, NU, 2 * E, S, tq);

  transpose_v<<<dim3(n / 64, E / 64), 256, 0, stream>>>(uv_bf, vT_bf, n, NU, E);

  // kernel = relu(q @ k^T / sqrt(128))^2   M=N=4096 K=128 (NT=2)
  gemm_pipe<1, 256><<<dim3(n / 256, n / 128), 512, 0, stream>>>(
      q_bf, S, k_bf, S, ker_bf, n, S, nullptr, nullptr, 0, nullptr, 0);

  // ug = u * (kernel @ v)   M=4096 N=2048 K=4096 (NT=64) ; 256 blocks
  gemm_pipe<2, 256><<<dim3(n / 256, E / 128), 512, 0, stream>>>(
      ker_bf, n, vT_bf, n, ug_bf, E, n, nullptr, uv_bf, NU, nullptr, 0);

  // out = ug @ o_w^T + o_b + x   M=4096 N=1024 K=2048 (NT=32) ; BM=128 -> 256 blocks
  gemm_pipe<3, 128><<<dim3(n / 128, H / 128), 512, 0, stream>>>(
      ug_bf, E, ow_bf, E, out, H, E, o_b, nullptr, 0, x, H);
}

// Round 6
// 191.715 us; speedup vs baseline: 1.4013x; 1.0436x over previous
//
#include <hip/hip_runtime.h>
#include <hip/hip_bf16.h>
#include <stdint.h>

// ---------- helpers ----------
typedef __attribute__((ext_vector_type(8))) int v8i;
typedef __attribute__((ext_vector_type(4))) float f32x4;

__device__ __forceinline__ unsigned short f2bf(float f) {
  union { float f; unsigned int u; } v; v.f = f;
  unsigned int r = (v.u + 0x7fffu + ((v.u >> 16) & 1u)) >> 16;
  return (unsigned short)r;
}
__device__ __forceinline__ float bf2f(unsigned short h) {
  union { float f; unsigned int u; } v; v.u = ((unsigned int)h) << 16; return v.f;
}
// fp8 e4m3 (OCP) converts via HW packer
__device__ __forceinline__ unsigned char f2fp8(float f) {
  int r = __builtin_amdgcn_cvt_pk_fp8_f32(f, 0.f, 0, false);
  return (unsigned char)(r & 0xff);
}
__device__ __forceinline__ unsigned int f2fp8x4(float a, float b, float c, float d) {
  int r = __builtin_amdgcn_cvt_pk_fp8_f32(a, b, 0, false);
  r = __builtin_amdgcn_cvt_pk_fp8_f32(c, d, r, true);
  return (unsigned int)r;
}

// async global->LDS, 16B per lane; lds base wave-uniform, HW adds lane*16
__device__ __forceinline__ void async_copy16(const unsigned char* g, unsigned char* lds_base) {
  __builtin_amdgcn_global_load_lds(
      (const __attribute__((address_space(1))) unsigned int*)g,
      (__attribute__((address_space(3))) unsigned int*)lds_base,
      16, 0, 0);
}

template <int N> __device__ __forceinline__ void wait_vmcnt() {
  if constexpr (N == 0)      asm volatile("s_waitcnt vmcnt(0)" ::: "memory");
  else if constexpr (N == 4) asm volatile("s_waitcnt vmcnt(4)" ::: "memory");
  else if constexpr (N == 6) asm volatile("s_waitcnt vmcnt(6)" ::: "memory");
  else static_assert(N == 0 || N == 4 || N == 6, "add vmcnt case");
}

// ---------- fp32 -> fp8 convert (two arrays, scale 16) ----------
__global__ __launch_bounds__(256) void cvt2_kernel(const float* __restrict__ s1,
                                                   unsigned int* __restrict__ d1, int n1_4,
                                                   const float* __restrict__ s2,
                                                   unsigned int* __restrict__ d2, int n2_4) {
  int i = blockIdx.x * 256 + threadIdx.x;
  const float* s; unsigned int* d; int idx;
  if (i < n1_4) { s = s1; d = d1; idx = i; }
  else if (i < n1_4 + n2_4) { s = s2; d = d2; idx = i - n1_4; }
  else return;
  float4 v = ((const float4*)s)[idx];
  d[idx] = f2fp8x4(v.x * 16.f, v.y * 16.f, v.z * 16.f, v.w * 16.f);
}

// ---------- LayerNorm: one block per row of 1024, fp8 out (scale 1) ----------
__global__ __launch_bounds__(256) void ln_kernel(const float* __restrict__ x,
                                                 const float* __restrict__ gamma,
                                                 const float* __restrict__ beta,
                                                 unsigned int* __restrict__ h) {
  const int row = blockIdx.x;
  const int t = threadIdx.x;
  const float4 v = ((const float4*)(x + (size_t)row * 1024))[t];
  float s  = v.x + v.y + v.z + v.w;
  float s2 = v.x*v.x + v.y*v.y + v.z*v.z + v.w*v.w;
#pragma unroll
  for (int o = 32; o > 0; o >>= 1) {
    s  += __shfl_down(s,  o, 64);
    s2 += __shfl_down(s2, o, 64);
  }
  __shared__ float rs[4], rs2[4];
  const int wid = t >> 6;
  if ((t & 63) == 0) { rs[wid] = s; rs2[wid] = s2; }
  __syncthreads();
  const float S  = rs[0] + rs[1] + rs[2] + rs[3];
  const float S2 = rs2[0] + rs2[1] + rs2[2] + rs2[3];
  const float mu  = S * (1.f / 1024.f);
  const float inv = rsqrtf(S2 * (1.f / 1024.f) - mu * mu + 1e-5f);
  const float4 g = ((const float4*)gamma)[t];
  const float4 b = ((const float4*)beta)[t];
  h[row * 256 + t] = f2fp8x4((v.x - mu) * inv * g.x + b.x,
                             (v.y - mu) * inv * g.y + b.y,
                             (v.z - mu) * inv * g.z + b.z,
                             (v.w - mu) * inv * g.w + b.w);
}

// ---------- q/k projection (fp8 out, scale 16) ----------
__global__ __launch_bounds__(256) void qk_kernel(const unsigned short* __restrict__ uv,
                                                 const float* __restrict__ qkw,
                                                 const float* __restrict__ qkb,
                                                 unsigned char* __restrict__ q,
                                                 unsigned char* __restrict__ k,
                                                 int NU, int baseoff, int S, int total) {
  int i = blockIdx.x * 256 + threadIdx.x;
  if (i < total) {
    int n = i / S, s = i - n * S;
    float base = bf2f(uv[(size_t)n * NU + baseoff + s]);
    q[i] = f2fp8(16.f * (base * qkw[s]     + qkb[s]));
    k[i] = f2fp8(16.f * (base * qkw[S + s] + qkb[S + s]));
  }
}

// ---------- transpose v: vT[e][m] = uv[m][E + e], fp8 out (scale 1) ----------
__global__ __launch_bounds__(256) void transpose_v(const unsigned short* __restrict__ uv,
                                                   unsigned char* __restrict__ vT,
                                                   int n, int NU, int E) {
  __shared__ unsigned short tile[64][68];
  const int tm = blockIdx.x * 64;
  const int te = blockIdx.y * 64;
  const int t = threadIdx.x;
  const int r  = t >> 4;
  const int c4 = (t & 15) * 4;
#pragma unroll
  for (int i = 0; i < 4; ++i) {
    int row = i * 16 + r;
    ushort4 v = *(const ushort4*)(uv + (size_t)(tm + row) * NU + E + te + c4);
    tile[row][c4 + 0] = v.x; tile[row][c4 + 1] = v.y;
    tile[row][c4 + 2] = v.z; tile[row][c4 + 3] = v.w;
  }
  __syncthreads();
#pragma unroll
  for (int i = 0; i < 4; ++i) {
    int erow = i * 16 + r;
    *(unsigned int*)(vT + (size_t)(te + erow) * n + tm + c4) =
        f2fp8x4(bf2f(tile[c4 + 0][erow]), bf2f(tile[c4 + 1][erow]),
                bf2f(tile[c4 + 2][erow]), bf2f(tile[c4 + 3][erow]));
  }
}

// ---------- fp8 MX GEMM: BMx128 tile, BK=128 (fp8 bytes), NBUF bufs, reg dbuf ----------
// Same schedule as the R5 bf16 pipe (proven): per K-tile one barrier,
// stage(t+2) -> counted vmcnt -> barrier -> ds_read frags(t+1) overlapping
// MFMA(t) -> lgkm(0) after MFMA. LDS rows are 128B (=BK fp8), identical byte
// geometry + XOR swizzle as before (both-sides, rule #21).
// MFMA: v_mfma_scale_f32_16x16x128_f8f6f4, fmt fp8/fp8, unit scales (0x7f).
// Per-lane frag = 32B at row (lane&15), K-window (lane>>4)*32, read as two
// b128 at slots (2g)^r7, (2g+1)^r7 (bit0 preserved; A/B use the same per-lane
// swap so the dot-product K pairing is preserved).
// NT==1 (GEMM2): single-buffer, no pipeline.
// EPI 0: silu(acc/16 + bias[col])      -> bf16 D   (A=h, B=16*uvw)
// EPI 1: 8*max(acc,0)^2               -> fp8 D    (= 2^26 * kernel_true)
// EPI 2: u * acc * 2^-2               -> fp8 D    (= 2^24 * ug_true)
// EPI 3: acc*2^-28 + bias[col] + X    -> f32 D
template <int EPI, int BM, int KTOT>
__global__ __launch_bounds__(512, 2) void gemm_f8(const unsigned char* __restrict__ A, int lda,
                                                  const unsigned char* __restrict__ B, int ldb,
                                                  void* __restrict__ D, int ldd,
                                                  const float* __restrict__ bias,
                                                  const unsigned short* __restrict__ U, int ldu,
                                                  const float* __restrict__ X, int ldx) {
  constexpr int NT   = KTOT / 128;
  static_assert(NT == 1 || (NT >= 3 && NT % 2 == 0), "NT must be 1 or even >=3");
  constexpr int NBUF = (NT == 1) ? 1 : 3;
  constexpr int AIT  = BM / 64;          // A gloads per tile
  constexpr int VMS  = AIT + 2;          // steady-state vmcnt (one tile in flight)
  constexpr int NN   = (BM == 256) ? 4 : 2;
  constexpr int WN   = NN * 16;

  __shared__ __align__(16) unsigned char As[NBUF][BM * 128];
  __shared__ __align__(16) unsigned char Bs[NBUF][128 * 128];

  const int tid  = threadIdx.x;
  const int wid  = tid >> 6;
  const int lane = tid & 63;
  const int bm = blockIdx.x * BM;
  const int bn = blockIdx.y * 128;
  const int wr = (BM == 256) ? (wid >> 1) : (wid >> 2);
  const int wc = (BM == 256) ? (wid & 1)  : (wid & 3);
  const int frow = lane & 15;
  const int r7   = frow & 7;
  const int kg   = lane >> 4;
  const int s0   = ((2 * kg)     ^ r7) * 16;   // byte slot of K-window lo half
  const int s1   = ((2 * kg + 1) ^ r7) * 16;   // byte slot of K-window hi half

  // staging: per gload instr, 512 threads cover 64 rows x 128B (wave = 8 rows);
  // LDS[row][slot] = G[row][slot ^ (row&7)] via pre-swizzled source
  const int srow  = tid >> 3;
  const int sslot = (tid & 7) ^ (srow & 7);
  const unsigned char* pA = A + (size_t)(bm + srow) * lda + sslot * 16;
  const unsigned char* pB = B + (size_t)(bn + srow) * ldb + sslot * 16;

  union F8 { v8i v; int4 q[2]; };

#define STAGE(bufidx, k0)                                                                     \
  {                                                                                           \
    _Pragma("unroll")                                                                         \
    for (int i = 0; i < AIT; ++i)                                                             \
      async_copy16(pA + (size_t)(i * 64) * lda + (k0), &As[bufidx][(i * 64 + wid * 8) * 128]);\
    _Pragma("unroll")                                                                         \
    for (int j = 0; j < 2; ++j)                                                               \
      async_copy16(pB + (size_t)(j * 64) * ldb + (k0), &Bs[bufidx][(j * 64 + wid * 8) * 128]);\
  }

#define READ_FRAGS(rbuf, FA, FB)                                                              \
  {                                                                                           \
    _Pragma("unroll")                                                                         \
    for (int m = 0; m < 4; ++m) {                                                             \
      const int base = (wr * 64 + m * 16 + frow) * 128;                                       \
      FA[m].q[0] = *(const int4*)&As[rbuf][base + s0];                                        \
      FA[m].q[1] = *(const int4*)&As[rbuf][base + s1];                                        \
    }                                                                                         \
    _Pragma("unroll")                                                                         \
    for (int n = 0; n < NN; ++n) {                                                            \
      const int base = (wc * WN + n * 16 + frow) * 128;                                       \
      FB[n].q[0] = *(const int4*)&Bs[rbuf][base + s0];                                        \
      FB[n].q[1] = *(const int4*)&Bs[rbuf][base + s1];                                        \
    }                                                                                         \
  }

#define MFMA_ALL(FA, FB)                                                                      \
  {                                                                                           \
    _Pragma("unroll")                                                                         \
    for (int m = 0; m < 4; ++m)                                                               \
      _Pragma("unroll")                                                                       \
      for (int n = 0; n < NN; ++n)                                                            \
        acc[m][n] = __builtin_amdgcn_mfma_scale_f32_16x16x128_f8f6f4(                         \
            FA[m].v, FB[n].v, acc[m][n], 0, 0, 0, 0x7f7f7f7f, 0, 0x7f7f7f7f);                 \
  }

#define PIPE_STEP(t, CA, CB, NA, NB)                                                          \
  {                                                                                           \
    if ((t) + 2 < NT) {                                                                       \
      STAGE(((t) + 2) % 3, ((size_t)((t) + 2)) << 7);                                         \
      wait_vmcnt<VMS>();                                                                      \
    } else {                                                                                  \
      wait_vmcnt<0>();                                                                        \
    }                                                                                         \
    __builtin_amdgcn_s_barrier();                                                             \
    __builtin_amdgcn_sched_barrier(0);                                                        \
    if ((t) + 1 < NT) { READ_FRAGS(((t) + 1) % 3, NA, NB); }                                  \
    __builtin_amdgcn_s_setprio(1);                                                            \
    MFMA_ALL(CA, CB);                                                                         \
    __builtin_amdgcn_s_setprio(0);                                                            \
    asm volatile("s_waitcnt lgkmcnt(0)" ::: "memory");                                        \
    __builtin_amdgcn_sched_barrier(0);                                                        \
  }

  f32x4 acc[4][NN] = {};
  F8 fa0[4], fb0[NN], fa1[4], fb1[NN];

  if constexpr (NT == 1) {
    STAGE(0, 0);
    wait_vmcnt<0>();
    __builtin_amdgcn_s_barrier();
    READ_FRAGS(0, fa0, fb0);
    asm volatile("s_waitcnt lgkmcnt(0)" ::: "memory");
    __builtin_amdgcn_sched_barrier(0);
    MFMA_ALL(fa0, fb0);
  } else {
    STAGE(0, 0);
    STAGE(1, 128);
    wait_vmcnt<VMS>();
    __builtin_amdgcn_s_barrier();
    __builtin_amdgcn_sched_barrier(0);
    READ_FRAGS(0, fa0, fb0);
    asm volatile("s_waitcnt lgkmcnt(0)" ::: "memory");
    __builtin_amdgcn_sched_barrier(0);
    for (int t = 0; t < NT; t += 2) {
      PIPE_STEP(t,     fa0, fb0, fa1, fb1);
      PIPE_STEP(t + 1, fa1, fb1, fa0, fb0);
    }
  }

#undef STAGE
#undef READ_FRAGS
#undef MFMA_ALL
#undef PIPE_STEP

  // epilogue (C/D layout: col=lane&15, row=(lane>>4)*4+r — shape-determined)
  const int rbase = (lane >> 4) * 4;
  const int cloc  = lane & 15;
#pragma unroll
  for (int m = 0; m < 4; ++m) {
#pragma unroll
    for (int n = 0; n < NN; ++n) {
      const int col = bn + wc * WN + n * 16 + cloc;
#pragma unroll
      for (int r = 0; r < 4; ++r) {
        const int row = bm + wr * 64 + m * 16 + rbase + r;
        float v = acc[m][n][r];
        if constexpr (EPI == 0) {
          v = v * (1.f / 16.f) + bias[col];
          float sv = v / (1.f + __expf(-v));
          ((unsigned short*)D)[(size_t)row * ldd + col] = f2bf(sv);
        } else if constexpr (EPI == 1) {
          float z = fmaxf(v, 0.f);
          ((unsigned char*)D)[(size_t)row * ldd + col] = f2fp8(8.f * z * z);
        } else if constexpr (EPI == 2) {
          float u = bf2f(U[(size_t)row * ldu + col]);
          ((unsigned char*)D)[(size_t)row * ldd + col] = f2fp8(u * v * 0.25f);
        } else {
          ((float*)D)[(size_t)row * ldd + col] =
              v * (1.f / 268435456.f) + bias[col] + X[(size_t)row * ldx + col];
        }
      }
    }
  }
}

// ---------- launch ----------
extern "C" void kernel_launch(void* const* d_in, const int* in_sizes, int n_in,
                              void* d_out, int out_size, void* d_ws, size_t ws_size,
                              hipStream_t stream) {
  const float* x    = (const float*)d_in[0];
  const float* ln_g = (const float*)d_in[1];
  const float* ln_b = (const float*)d_in[2];
  const float* uv_w = (const float*)d_in[3];
  const float* uv_b = (const float*)d_in[4];
  const float* qk_w = (const float*)d_in[5];
  const float* qk_b = (const float*)d_in[6];
  const float* o_w  = (const float*)d_in[7];
  const float* o_b  = (const float*)d_in[8];
  float* out = (float*)d_out;

  const int H = 1024, E = 2048, S = 128;
  const int NU = 2 * E + S;          // 4224
  const int n = in_sizes[0] / H;     // 4096

  char* p = (char*)d_ws;
  unsigned char* h_f8   = (unsigned char*)p; p += (size_t)n * H;
  unsigned char* uvw_f8 = (unsigned char*)p; p += (size_t)NU * H;
  unsigned char* ow_f8  = (unsigned char*)p; p += (size_t)H * E;
  unsigned short* uv_bf = (unsigned short*)p; p += (size_t)n * NU * 2;
  unsigned char* q_f8   = (unsigned char*)p; p += (size_t)n * S;
  unsigned char* k_f8   = (unsigned char*)p; p += (size_t)n * S;
  unsigned char* vT_f8  = (unsigned char*)p; p += (size_t)E * n;
  unsigned char* ker_f8 = (unsigned char*)p; p += (size_t)n * n;
  unsigned char* ug_f8  = (unsigned char*)p; p += (size_t)n * E;

  const int n1_4 = NU * H / 4, n2_4 = H * E / 4;
  cvt2_kernel<<<(n1_4 + n2_4 + 255) / 256, 256, 0, stream>>>(
      uv_w, (unsigned int*)uvw_f8, n1_4, o_w, (unsigned int*)ow_f8, n2_4);

  ln_kernel<<<n, 256, 0, stream>>>(x, ln_g, ln_b, (unsigned int*)h_f8);

  // uv = silu(h @ uv_w^T + uv_b)   M=4096 N=4224 K=1024 (NT=8)
  gemm_f8<0, 256, 1024><<<dim3(n / 256, NU / 128), 512, 0, stream>>>(
      h_f8, H, uvw_f8, H, uv_bf, NU, uv_b, nullptr, 0, nullptr, 0);

  int tq = n * S;
  qk_kernel<<<(tq + 255) / 256, 256, 0, stream>>>(uv_bf, qk_w, qk_b, q_f8, k_f8, NU, 2 * E, S, tq);

  transpose_v<<<dim3(n / 64, E / 64), 256, 0, stream>>>(uv_bf, vT_f8, n, NU, E);

  // ker_f8 = 2^26 * relu(qk/sqrt(128))^2   M=N=4096 K=128 (NT=1)
  gemm_f8<1, 256, 128><<<dim3(n / 256, n / 128), 512, 0, stream>>>(
      q_f8, S, k_f8, S, ker_f8, n, nullptr, nullptr, 0, nullptr, 0);

  // ug_f8 = 2^24 * u * (kernel @ v)   M=4096 N=2048 K=4096 (NT=32)
  gemm_f8<2, 256, 4096><<<dim3(n / 256, E / 128), 512, 0, stream>>>(
      ker_f8, n, vT_f8, n, ug_f8, E, nullptr, uv_bf, NU, nullptr, 0);

  // out = ug @ o_w^T + o_b + x   M=4096 N=1024 K=2048 (NT=16)
  gemm_f8<3, 128, 2048><<<dim3(n / 128, H / 128), 512, 0, stream>>>(
      ug_f8, E, ow_f8, E, out, H, o_b, nullptr, 0, x, H);
}

// Round 7
// 186.407 us; speedup vs baseline: 1.4412x; 1.0285x over previous
//
#include <hip/hip_runtime.h>
#include <hip/hip_bf16.h>
#include <stdint.h>

// ---------- helpers ----------
typedef __attribute__((ext_vector_type(8))) int v8i;
typedef __attribute__((ext_vector_type(4))) float f32x4;

__device__ __forceinline__ unsigned short f2bf(float f) {
  union { float f; unsigned int u; } v; v.f = f;
  unsigned int r = (v.u + 0x7fffu + ((v.u >> 16) & 1u)) >> 16;
  return (unsigned short)r;
}
__device__ __forceinline__ float bf2f(unsigned short h) {
  union { float f; unsigned int u; } v; v.u = ((unsigned int)h) << 16; return v.f;
}
// fp8 e4m3 (OCP) converts via HW packer
__device__ __forceinline__ unsigned char f2fp8(float f) {
  int r = __builtin_amdgcn_cvt_pk_fp8_f32(f, 0.f, 0, false);
  return (unsigned char)(r & 0xff);
}
__device__ __forceinline__ unsigned int f2fp8x4(float a, float b, float c, float d) {
  int r = __builtin_amdgcn_cvt_pk_fp8_f32(a, b, 0, false);
  r = __builtin_amdgcn_cvt_pk_fp8_f32(c, d, r, true);
  return (unsigned int)r;
}

// async global->LDS, 16B per lane; lds base wave-uniform, HW adds lane*16
__device__ __forceinline__ void async_copy16(const unsigned char* g, unsigned char* lds_base) {
  __builtin_amdgcn_global_load_lds(
      (const __attribute__((address_space(1))) unsigned int*)g,
      (__attribute__((address_space(3))) unsigned int*)lds_base,
      16, 0, 0);
}

template <int N> __device__ __forceinline__ void wait_vmcnt() {
  if constexpr (N == 0)      asm volatile("s_waitcnt vmcnt(0)" ::: "memory");
  else if constexpr (N == 4) asm volatile("s_waitcnt vmcnt(4)" ::: "memory");
  else if constexpr (N == 6) asm volatile("s_waitcnt vmcnt(6)" ::: "memory");
  else static_assert(N == 0 || N == 4 || N == 6, "add vmcnt case");
}

// ---------- fp32 -> fp8 convert (two arrays, scale 16) ----------
__global__ __launch_bounds__(256) void cvt2_kernel(const float* __restrict__ s1,
                                                   unsigned int* __restrict__ d1, int n1_4,
                                                   const float* __restrict__ s2,
                                                   unsigned int* __restrict__ d2, int n2_4) {
  int i = blockIdx.x * 256 + threadIdx.x;
  const float* s; unsigned int* d; int idx;
  if (i < n1_4) { s = s1; d = d1; idx = i; }
  else if (i < n1_4 + n2_4) { s = s2; d = d2; idx = i - n1_4; }
  else return;
  float4 v = ((const float4*)s)[idx];
  d[idx] = f2fp8x4(v.x * 16.f, v.y * 16.f, v.z * 16.f, v.w * 16.f);
}

// ---------- LayerNorm: one block per row of 1024, fp8 out (scale 1) ----------
__global__ __launch_bounds__(256) void ln_kernel(const float* __restrict__ x,
                                                 const float* __restrict__ gamma,
                                                 const float* __restrict__ beta,
                                                 unsigned int* __restrict__ h) {
  const int row = blockIdx.x;
  const int t = threadIdx.x;
  const float4 v = ((const float4*)(x + (size_t)row * 1024))[t];
  float s  = v.x + v.y + v.z + v.w;
  float s2 = v.x*v.x + v.y*v.y + v.z*v.z + v.w*v.w;
#pragma unroll
  for (int o = 32; o > 0; o >>= 1) {
    s  += __shfl_down(s,  o, 64);
    s2 += __shfl_down(s2, o, 64);
  }
  __shared__ float rs[4], rs2[4];
  const int wid = t >> 6;
  if ((t & 63) == 0) { rs[wid] = s; rs2[wid] = s2; }
  __syncthreads();
  const float S  = rs[0] + rs[1] + rs[2] + rs[3];
  const float S2 = rs2[0] + rs2[1] + rs2[2] + rs2[3];
  const float mu  = S * (1.f / 1024.f);
  const float inv = rsqrtf(S2 * (1.f / 1024.f) - mu * mu + 1e-5f);
  const float4 g = ((const float4*)gamma)[t];
  const float4 b = ((const float4*)beta)[t];
  h[row * 256 + t] = f2fp8x4((v.x - mu) * inv * g.x + b.x,
                             (v.y - mu) * inv * g.y + b.y,
                             (v.z - mu) * inv * g.z + b.z,
                             (v.w - mu) * inv * g.w + b.w);
}

// ---------- q/k projection (fp8 out, scale 16) ----------
__global__ __launch_bounds__(256) void qk_kernel(const unsigned short* __restrict__ uv,
                                                 const float* __restrict__ qkw,
                                                 const float* __restrict__ qkb,
                                                 unsigned char* __restrict__ q,
                                                 unsigned char* __restrict__ k,
                                                 int NU, int baseoff, int S, int total) {
  int i = blockIdx.x * 256 + threadIdx.x;
  if (i < total) {
    int n = i / S, s = i - n * S;
    float base = bf2f(uv[(size_t)n * NU + baseoff + s]);
    q[i] = f2fp8(16.f * (base * qkw[s]     + qkb[s]));
    k[i] = f2fp8(16.f * (base * qkw[S + s] + qkb[S + s]));
  }
}

// ---------- transpose v: vT[e][m] = uv[m][E + e], fp8 out (scale 1) ----------
__global__ __launch_bounds__(256) void transpose_v(const unsigned short* __restrict__ uv,
                                                   unsigned char* __restrict__ vT,
                                                   int n, int NU, int E) {
  __shared__ unsigned short tile[64][68];
  const int tm = blockIdx.x * 64;
  const int te = blockIdx.y * 64;
  const int t = threadIdx.x;
  const int r  = t >> 4;
  const int c4 = (t & 15) * 4;
#pragma unroll
  for (int i = 0; i < 4; ++i) {
    int row = i * 16 + r;
    ushort4 v = *(const ushort4*)(uv + (size_t)(tm + row) * NU + E + te + c4);
    tile[row][c4 + 0] = v.x; tile[row][c4 + 1] = v.y;
    tile[row][c4 + 2] = v.z; tile[row][c4 + 3] = v.w;
  }
  __syncthreads();
#pragma unroll
  for (int i = 0; i < 4; ++i) {
    int erow = i * 16 + r;
    *(unsigned int*)(vT + (size_t)(te + erow) * n + tm + c4) =
        f2fp8x4(bf2f(tile[c4 + 0][erow]), bf2f(tile[c4 + 1][erow]),
                bf2f(tile[c4 + 2][erow]), bf2f(tile[c4 + 3][erow]));
  }
}

// ---------- fp8 MX GEMM: BMx128 tile, BK=128 bytes, NBUF bufs, reg dbuf ----------
// R5-proven schedule: per K-tile ONE barrier; stage(t+2) -> counted vmcnt ->
// barrier -> ds_read frags(t+1) overlapping MFMA(t) -> lgkm(0) after MFMA.
// LDS rows 128B. Swizzle in 32B UNITS so each lane's 32B fragment is one
// contiguous v8i load (2 adjacent ds_read_b128 -> 8 VGPRs, NO aggregates /
// scratch — the R6 union demoted frags to scratch, VGPR=128, MfmaUtil 12%).
// Read: lane(kg=lane>>4, row=lane&15) loads LDS[row][unit (kg^(row&3))*32],
// which holds G[row][K-window kg] (source slot16 pre-XOR'd by (row&3)<<1;
// both-sides, rule #21; exact K-windows — no K permutation at all).
// MFMA: v_mfma_scale_f32_16x16x128_f8f6f4, fp8/fp8, unit scales 0x7f.
// EPI 0: silu(acc/16 + bias[col])      -> bf16 D   (A=h, B=16*uvw)
// EPI 1: 8*max(acc,0)^2               -> fp8 D    (= 2^26 * kernel_true)
// EPI 2: u * acc * 2^-2               -> fp8 D    (= 2^24 * ug_true)
// EPI 3: acc*2^-28 + bias[col] + X    -> f32 D
template <int EPI, int BM, int KTOT>
__global__ __launch_bounds__(512, 2) void gemm_f8(const unsigned char* __restrict__ A, int lda,
                                                  const unsigned char* __restrict__ B, int ldb,
                                                  void* __restrict__ D, int ldd,
                                                  const float* __restrict__ bias,
                                                  const unsigned short* __restrict__ U, int ldu,
                                                  const float* __restrict__ X, int ldx) {
  constexpr int NT   = KTOT / 128;
  static_assert(NT == 1 || (NT >= 3 && NT % 2 == 0), "NT must be 1 or even >=3");
  constexpr int NBUF = (NT == 1) ? 1 : 3;
  constexpr int AIT  = BM / 64;          // A gloads per tile
  constexpr int VMS  = AIT + 2;          // steady-state vmcnt (one tile in flight)
  constexpr int NN   = (BM == 256) ? 4 : 2;
  constexpr int WN   = NN * 16;

  __shared__ __align__(64) unsigned char As[NBUF][BM * 128];
  __shared__ __align__(64) unsigned char Bs[NBUF][128 * 128];

  const int tid  = threadIdx.x;
  const int wid  = tid >> 6;
  const int lane = tid & 63;
  const int bm = blockIdx.x * BM;
  const int bn = blockIdx.y * 128;
  const int wr = (BM == 256) ? (wid >> 1) : (wid >> 2);
  const int wc = (BM == 256) ? (wid & 1)  : (wid & 3);
  const int frow = lane & 15;
  const int kg   = lane >> 4;
  const int funit = (kg ^ (frow & 3)) << 5;    // 32B-unit swizzled frag byte offset

  // staging: per gload instr, 512 threads cover 64 rows x 128B (wave = 8 rows);
  // LDS[row][slot16] = G[row][slot16 ^ ((row&3)<<1)] via pre-swizzled source
  const int srow  = tid >> 3;
  const int sslot = (tid & 7) ^ ((srow & 3) << 1);
  const unsigned char* pA = A + (size_t)(bm + srow) * lda + sslot * 16;
  const unsigned char* pB = B + (size_t)(bn + srow) * ldb + sslot * 16;

#define STAGE(bufidx, k0)                                                                     \
  {                                                                                           \
    _Pragma("unroll")                                                                         \
    for (int i = 0; i < AIT; ++i)                                                             \
      async_copy16(pA + (size_t)(i * 64) * lda + (k0), &As[bufidx][(i * 64 + wid * 8) * 128]);\
    _Pragma("unroll")                                                                         \
    for (int j = 0; j < 2; ++j)                                                               \
      async_copy16(pB + (size_t)(j * 64) * ldb + (k0), &Bs[bufidx][(j * 64 + wid * 8) * 128]);\
  }

#define READ_FRAGS(rbuf, FA, FB)                                                              \
  {                                                                                           \
    _Pragma("unroll")                                                                         \
    for (int m = 0; m < 4; ++m)                                                               \
      FA[m] = *(const v8i*)&As[rbuf][(wr * 64 + m * 16 + frow) * 128 + funit];                \
    _Pragma("unroll")                                                                         \
    for (int n = 0; n < NN; ++n)                                                              \
      FB[n] = *(const v8i*)&Bs[rbuf][(wc * WN + n * 16 + frow) * 128 + funit];                \
  }

#define MFMA_ALL(FA, FB)                                                                      \
  {                                                                                           \
    _Pragma("unroll")                                                                         \
    for (int m = 0; m < 4; ++m)                                                               \
      _Pragma("unroll")                                                                       \
      for (int n = 0; n < NN; ++n)                                                            \
        acc[m][n] = __builtin_amdgcn_mfma_scale_f32_16x16x128_f8f6f4(                         \
            FA[m], FB[n], acc[m][n], 0, 0, 0, 0x7f7f7f7f, 0, 0x7f7f7f7f);                     \
  }

#define PIPE_STEP(t, CA, CB, NA, NB)                                                          \
  {                                                                                           \
    if ((t) + 2 < NT) {                                                                       \
      STAGE(((t) + 2) % 3, ((size_t)((t) + 2)) << 7);                                         \
      wait_vmcnt<VMS>();                                                                      \
    } else {                                                                                  \
      wait_vmcnt<0>();                                                                        \
    }                                                                                         \
    __builtin_amdgcn_s_barrier();                                                             \
    __builtin_amdgcn_sched_barrier(0);                                                        \
    if ((t) + 1 < NT) { READ_FRAGS(((t) + 1) % 3, NA, NB); }                                  \
    __builtin_amdgcn_s_setprio(1);                                                            \
    MFMA_ALL(CA, CB);                                                                         \
    __builtin_amdgcn_s_setprio(0);                                                            \
    asm volatile("s_waitcnt lgkmcnt(0)" ::: "memory");                                        \
    __builtin_amdgcn_sched_barrier(0);                                                        \
  }

  f32x4 acc[4][NN] = {};
  v8i fa0[4], fb0[NN], fa1[4], fb1[NN];

  if constexpr (NT == 1) {
    STAGE(0, 0);
    wait_vmcnt<0>();
    __builtin_amdgcn_s_barrier();
    READ_FRAGS(0, fa0, fb0);
    asm volatile("s_waitcnt lgkmcnt(0)" ::: "memory");
    __builtin_amdgcn_sched_barrier(0);
    MFMA_ALL(fa0, fb0);
  } else {
    STAGE(0, 0);
    STAGE(1, 128);
    wait_vmcnt<VMS>();
    __builtin_amdgcn_s_barrier();
    __builtin_amdgcn_sched_barrier(0);
    READ_FRAGS(0, fa0, fb0);
    asm volatile("s_waitcnt lgkmcnt(0)" ::: "memory");
    __builtin_amdgcn_sched_barrier(0);
    for (int t = 0; t < NT; t += 2) {
      PIPE_STEP(t,     fa0, fb0, fa1, fb1);
      PIPE_STEP(t + 1, fa1, fb1, fa0, fb0);
    }
  }

#undef STAGE
#undef READ_FRAGS
#undef MFMA_ALL
#undef PIPE_STEP

  // epilogue (C/D layout: col=lane&15, row=(lane>>4)*4+r — shape-determined)
  const int rbase = (lane >> 4) * 4;
  const int cloc  = lane & 15;
#pragma unroll
  for (int m = 0; m < 4; ++m) {
#pragma unroll
    for (int n = 0; n < NN; ++n) {
      const int col = bn + wc * WN + n * 16 + cloc;
#pragma unroll
      for (int r = 0; r < 4; ++r) {
        const int row = bm + wr * 64 + m * 16 + rbase + r;
        float v = acc[m][n][r];
        if constexpr (EPI == 0) {
          v = v * (1.f / 16.f) + bias[col];
          float sv = v / (1.f + __expf(-v));
          ((unsigned short*)D)[(size_t)row * ldd + col] = f2bf(sv);
        } else if constexpr (EPI == 1) {
          float z = fmaxf(v, 0.f);
          ((unsigned char*)D)[(size_t)row * ldd + col] = f2fp8(8.f * z * z);
        } else if constexpr (EPI == 2) {
          float u = bf2f(U[(size_t)row * ldu + col]);
          ((unsigned char*)D)[(size_t)row * ldd + col] = f2fp8(u * v * 0.25f);
        } else {
          ((float*)D)[(size_t)row * ldd + col] =
              v * (1.f / 268435456.f) + bias[col] + X[(size_t)row * ldx + col];
        }
      }
    }
  }
}

// ---------- launch ----------
extern "C" void kernel_launch(void* const* d_in, const int* in_sizes, int n_in,
                              void* d_out, int out_size, void* d_ws, size_t ws_size,
                              hipStream_t stream) {
  const float* x    = (const float*)d_in[0];
  const float* ln_g = (const float*)d_in[1];
  const float* ln_b = (const float*)d_in[2];
  const float* uv_w = (const float*)d_in[3];
  const float* uv_b = (const float*)d_in[4];
  const float* qk_w = (const float*)d_in[5];
  const float* qk_b = (const float*)d_in[6];
  const float* o_w  = (const float*)d_in[7];
  const float* o_b  = (const float*)d_in[8];
  float* out = (float*)d_out;

  const int H = 1024, E = 2048, S = 128;
  const int NU = 2 * E + S;          // 4224
  const int n = in_sizes[0] / H;     // 4096

  char* p = (char*)d_ws;
  unsigned char* h_f8   = (unsigned char*)p; p += (size_t)n * H;
  unsigned char* uvw_f8 = (unsigned char*)p; p += (size_t)NU * H;
  unsigned char* ow_f8  = (unsigned char*)p; p += (size_t)H * E;
  unsigned short* uv_bf = (unsigned short*)p; p += (size_t)n * NU * 2;
  unsigned char* q_f8   = (unsigned char*)p; p += (size_t)n * S;
  unsigned char* k_f8   = (unsigned char*)p; p += (size_t)n * S;
  unsigned char* vT_f8  = (unsigned char*)p; p += (size_t)E * n;
  unsigned char* ker_f8 = (unsigned char*)p; p += (size_t)n * n;
  unsigned char* ug_f8  = (unsigned char*)p; p += (size_t)n * E;

  const int n1_4 = NU * H / 4, n2_4 = H * E / 4;
  cvt2_kernel<<<(n1_4 + n2_4 + 255) / 256, 256, 0, stream>>>(
      uv_w, (unsigned int*)uvw_f8, n1_4, o_w, (unsigned int*)ow_f8, n2_4);

  ln_kernel<<<n, 256, 0, stream>>>(x, ln_g, ln_b, (unsigned int*)h_f8);

  // uv = silu(h @ uv_w^T + uv_b)   M=4096 N=4224 K=1024 (NT=8)
  gemm_f8<0, 256, 1024><<<dim3(n / 256, NU / 128), 512, 0, stream>>>(
      h_f8, H, uvw_f8, H, uv_bf, NU, uv_b, nullptr, 0, nullptr, 0);

  int tq = n * S;
  qk_kernel<<<(tq + 255) / 256, 256, 0, stream>>>(uv_bf, qk_w, qk_b, q_f8, k_f8, NU, 2 * E, S, tq);

  transpose_v<<<dim3(n / 64, E / 64), 256, 0, stream>>>(uv_bf, vT_f8, n, NU, E);

  // ker_f8 = 2^26 * relu(qk/sqrt(128))^2   M=N=4096 K=128 (NT=1)
  gemm_f8<1, 256, 128><<<dim3(n / 256, n / 128), 512, 0, stream>>>(
      q_f8, S, k_f8, S, ker_f8, n, nullptr, nullptr, 0, nullptr, 0);

  // ug_f8 = 2^24 * u * (kernel @ v)   M=4096 N=2048 K=4096 (NT=32)
  gemm_f8<2, 256, 4096><<<dim3(n / 256, E / 128), 512, 0, stream>>>(
      ker_f8, n, vT_f8, n, ug_f8, E, nullptr, uv_bf, NU, nullptr, 0);

  // out = ug @ o_w^T + o_b + x   M=4096 N=1024 K=2048 (NT=16)
  gemm_f8<3, 128, 2048><<<dim3(n / 128, H / 128), 512, 0, stream>>>(
      ug_f8, E, ow_f8, E, out, H, o_b, nullptr, 0, x, H);
}